// Round 1
// baseline (421.796 us; speedup 1.0000x reference)
//
#include <hip/hip_runtime.h>

#define HH 64
#define TT 512
#define BB 16

typedef __attribute__((ext_vector_type(8))) short short8;
typedef __attribute__((ext_vector_type(4))) float f32x4;

static __device__ __forceinline__ unsigned short f2bf(float f) {
  unsigned u = __float_as_uint(f);
  u += 0x7fffu + ((u >> 16) & 1u);   // round-to-nearest-even
  return (unsigned short)(u >> 16);
}

static __device__ __forceinline__ float sigm(float x) {
  float e = __builtin_amdgcn_exp2f(-1.442695041f * x);
  return __builtin_amdgcn_rcpf(1.0f + e);
}
static __device__ __forceinline__ float tanh_fast(float x) {
  float e = __builtin_amdgcn_exp2f(2.885390082f * x);
  return 1.0f - 2.0f * __builtin_amdgcn_rcpf(1.0f + e);
}

static __device__ __forceinline__ short8 pack8(const float* __restrict__ p) {
  const float4* p4 = (const float4*)p;
  float4 a = p4[0], b = p4[1];
  short8 r;
  r[0] = (short)f2bf(a.x); r[1] = (short)f2bf(a.y);
  r[2] = (short)f2bf(a.z); r[3] = (short)f2bf(a.w);
  r[4] = (short)f2bf(b.x); r[5] = (short)f2bf(b.y);
  r[6] = (short)f2bf(b.z); r[7] = (short)f2bf(b.w);
  return r;
}

// A-fragment read: lane needs h[row=m][k0 .. k0+7], k0 = kt*32 + q*8, bf16.
// Row stride 128B; 16B blocks XOR-swizzled by (row&7)<<4 to kill bank conflicts.
static __device__ __forceinline__ short8 ldfrag(const unsigned short* buf, int m, int q, int kt) {
  const int off = (kt * 64 + q * 16) ^ ((m & 7) << 4);
  return *(const short8*)((const char*)buf + m * 128 + off);
}

__global__ __launch_bounds__(512)
void lstm2_fused(const float* __restrict__ x,
                 const float* __restrict__ Wih0, const float* __restrict__ Whh0,
                 const float* __restrict__ bih0, const float* __restrict__ bhh0,
                 const float* __restrict__ Wih1, const float* __restrict__ Whh1,
                 const float* __restrict__ bih1, const float* __restrict__ bhh1,
                 const float* __restrict__ Wfc,  const float* __restrict__ bfc,
                 float* __restrict__ out)
{
  __shared__ float xs[TT * BB];                            // 32 KB, xs[t][row]
  __shared__ __align__(16) unsigned short h0buf[BB * HH];  // 2 KB bf16, swizzled
  __shared__ __align__(16) unsigned short h1buf[BB * HH];  // 2 KB bf16, swizzled
  __shared__ float h1f[BB * HH];                           // 4 KB fp32 final h1

  const int tid  = threadIdx.x;
  const int wave = tid >> 6;
  const int lane = tid & 63;
  const int grp  = wave >> 2;      // 0: layer0 waves, 1: layer1 waves
  const int w    = wave & 3;       // column-block within group
  const int m    = lane & 15;
  const int q    = lane >> 4;
  const int b0   = blockIdx.x * BB;

  // ---- stage x transposed: xs[t][r] = x[b0+r][t] ----
  {
    const int t = tid;             // blockDim.x == 512 == TT
    #pragma unroll
    for (int r = 0; r < BB; ++r)
      xs[t * BB + r] = x[(size_t)(b0 + r) * TT + t];
  }
  // zero h state (bf16 zero == 0x0000)
  h0buf[tid] = 0; h0buf[tid + 512] = 0;
  h1buf[tid] = 0; h1buf[tid + 512] = 0;

  // ---- pack weight B-fragments into registers (held across the whole loop) ----
  // wave w owns gate n-tiles {4n+w}: n=0->i, 1->f, 2->g, 3->o, cols 16w..16w+15 of each gate.
  // B-frag layout: lane holds Wmat[col=16*tile+m][k0 + j], j=0..7, k0 = kt*32 + q*8.
  short8 wf[16];
  float bsum[4], wx[4];
  #pragma unroll
  for (int n = 0; n < 4; ++n) {
    const int colg = 16 * (4 * n + w) + m;
    if (grp == 0) {
      bsum[n] = bih0[colg] + bhh0[colg];
      wx[n]   = Wih0[colg];
      #pragma unroll
      for (int kt = 0; kt < 2; ++kt)
        wf[n * 2 + kt] = pack8(Whh0 + colg * HH + kt * 32 + q * 8);
    } else {
      bsum[n] = bih1[colg] + bhh1[colg];
      wx[n]   = 0.f;
      #pragma unroll
      for (int kt = 0; kt < 4; ++kt) {   // kt 0,1: Wih1 (h0 input), kt 2,3: Whh1 (h1 recurrent)
        const float* Wsrc = (kt < 2) ? Wih1 : Whh1;
        wf[n * 4 + kt] = pack8(Wsrc + colg * HH + (kt & 1) * 32 + q * 8);
      }
    }
  }

  __syncthreads();   // x staged + h zeroed before first iteration reads

  float cst[4] = {0.f, 0.f, 0.f, 0.f};
  const int colw = 16 * w + m;          // my h column within [0,64)

  // iteration t: group A computes L0 step t (needs h0(t-1));
  //              group B computes L1 step t-1 (needs h0(t-1), h1(t-2)).
  for (int t = 0; t <= TT; ++t) {
    const bool actA = (grp == 0) && (t < TT);
    const bool actB = (grp == 1) && (t >= 1);
    short8 af0, af1, af2, af3;
    if (actA) {
      af0 = ldfrag(h0buf, m, q, 0);
      af1 = ldfrag(h0buf, m, q, 1);
    } else if (actB) {
      af0 = ldfrag(h0buf, m, q, 0);
      af1 = ldfrag(h0buf, m, q, 1);
      af2 = ldfrag(h1buf, m, q, 0);
      af3 = ldfrag(h1buf, m, q, 1);
    }
    __syncthreads();   // all reads of h0/h1 done before anyone overwrites

    if (actA) {
      f32x4 acc[4];
      float xv[4];
      #pragma unroll
      for (int j = 0; j < 4; ++j) xv[j] = xs[t * BB + q * 4 + j];
      #pragma unroll
      for (int n = 0; n < 4; ++n) {
        #pragma unroll
        for (int j = 0; j < 4; ++j) acc[n][j] = fmaf(xv[j], wx[n], bsum[n]);
      }
      #pragma unroll
      for (int n = 0; n < 4; ++n) {
        acc[n] = __builtin_amdgcn_mfma_f32_16x16x32_bf16(af0, wf[n*2+0], acc[n], 0, 0, 0);
        acc[n] = __builtin_amdgcn_mfma_f32_16x16x32_bf16(af1, wf[n*2+1], acc[n], 0, 0, 0);
      }
      #pragma unroll
      for (int j = 0; j < 4; ++j) {
        float iv = sigm(acc[0][j]);
        float fv = sigm(acc[1][j]);
        float gv = tanh_fast(acc[2][j]);
        float ov = sigm(acc[3][j]);
        float c  = fmaf(fv, cst[j], iv * gv);
        cst[j] = c;
        float h  = ov * tanh_fast(c);
        const int row = q * 4 + j;
        const int off = (2 * colw) ^ ((row & 7) << 4);
        *(unsigned short*)((char*)h0buf + row * 128 + off) = f2bf(h);
      }
    } else if (actB) {
      f32x4 acc[4];
      #pragma unroll
      for (int n = 0; n < 4; ++n) {
        acc[n][0] = bsum[n]; acc[n][1] = bsum[n]; acc[n][2] = bsum[n]; acc[n][3] = bsum[n];
      }
      #pragma unroll
      for (int n = 0; n < 4; ++n) {
        acc[n] = __builtin_amdgcn_mfma_f32_16x16x32_bf16(af0, wf[n*4+0], acc[n], 0, 0, 0);
        acc[n] = __builtin_amdgcn_mfma_f32_16x16x32_bf16(af1, wf[n*4+1], acc[n], 0, 0, 0);
        acc[n] = __builtin_amdgcn_mfma_f32_16x16x32_bf16(af2, wf[n*4+2], acc[n], 0, 0, 0);
        acc[n] = __builtin_amdgcn_mfma_f32_16x16x32_bf16(af3, wf[n*4+3], acc[n], 0, 0, 0);
      }
      const bool last = (t == TT);
      #pragma unroll
      for (int j = 0; j < 4; ++j) {
        float iv = sigm(acc[0][j]);
        float fv = sigm(acc[1][j]);
        float gv = tanh_fast(acc[2][j]);
        float ov = sigm(acc[3][j]);
        float c  = fmaf(fv, cst[j], iv * gv);
        cst[j] = c;
        float h  = ov * tanh_fast(c);
        const int row = q * 4 + j;
        const int off = (2 * colw) ^ ((row & 7) << 4);
        *(unsigned short*)((char*)h1buf + row * 128 + off) = f2bf(h);
        if (last) h1f[row * HH + colw] = h;
      }
    }
    __syncthreads();   // writes visible for next iteration's readers
  }

  // ---- FC epilogue: out[b][o] = h1_final[b] . Wfc[o] + bfc[o] ----
  if (tid < BB * 7) {
    const int b = tid / 7, o = tid % 7;
    float s = bfc[o];
    #pragma unroll
    for (int k = 0; k < HH; ++k) s = fmaf(h1f[b * HH + k], Wfc[o * HH + k], s);
    out[(size_t)(b0 + b) * 7 + o] = s;
  }
}

extern "C" void kernel_launch(void* const* d_in, const int* in_sizes, int n_in,
                              void* d_out, int out_size, void* d_ws, size_t ws_size,
                              hipStream_t stream) {
  const float* x    = (const float*)d_in[0];
  const float* Wih0 = (const float*)d_in[1];
  const float* Whh0 = (const float*)d_in[2];
  const float* bih0 = (const float*)d_in[3];
  const float* bhh0 = (const float*)d_in[4];
  const float* Wih1 = (const float*)d_in[5];
  const float* Whh1 = (const float*)d_in[6];
  const float* bih1 = (const float*)d_in[7];
  const float* bhh1 = (const float*)d_in[8];
  const float* Wfc  = (const float*)d_in[9];
  const float* bfc  = (const float*)d_in[10];
  float* out = (float*)d_out;

  dim3 grid(4096 / BB);   // 256 workgroups, 1 per CU
  dim3 block(512);        // 8 waves: 4 layer-0 + 4 layer-1 (pipelined)
  hipLaunchKernelGGL(lstm2_fused, grid, block, 0, stream,
                     x, Wih0, Whh0, bih0, bhh0, Wih1, Whh1, bih1, bhh1, Wfc, bfc, out);
}